// Round 6
// baseline (1215.199 us; speedup 1.0000x reference)
//
#include <hip/hip_runtime.h>

// MultiGNN: B=256, A=64 -> 16384 images of 8x15x15
// convs: 8->16 (15->13), 16->32 (13->11), 32->16 (11->9), 16->32 (9->7)
// flatten 32*7*7=1568 -> MLP 128,128,128 -> GCN over 64 agents, E=128
//
// Conv kernel v4: 2 images/block, 62KB aliased LDS arena.
//  - skewed L0OUT row layout y*16 + (y>>1)*4 (monotone! R5's (y>>1)&3 wrapped
//    at y=8 and overlapped rows 7/8): wave's 8 y-rows hit the 8 disjoint
//    4-bank windows {0,16,4,20,8,24,12,28} -> no read conflicts in L1
//  - cc-major accumulators -> float4 LDS writes
//  - unroll-2 ci loop -> pipelines weight global loads + LDS reads

#define NIMG 16384

// ---------------- LDS arena layout (floats) --------------------------------
// region A @0    : IN (2x2400, rs20) / L1OUT (2x4224=8448, rs12,pl132)
//                  / L3OUT+L3P (2x1792 + 2x1792, rs8,pl56)
// region B @8448 : L0OUT (2x3712, skewed rs16+(y>>1)*4, pl232)  ends 15872
//                  / L2OUT+L2P (2x1728 + 2x1728, rs12,pl108)    ends 15360
#define ARENA_F 15872
#define OFF_IN    0
#define OFF_L0    8448
#define OFF_L1    0
#define OFF_L2    8448
#define OFF_L2P   11904
#define OFF_L3    0
#define OFF_L3P   3584

// ---------------------------------------------------------------------------
// One-time weight transpose: wt[l][r][co] = cw[l][co][r], r = ci*9+ky*3+kx
// ---------------------------------------------------------------------------
__global__ __launch_bounds__(256) void transpose_w(
    const float* __restrict__ c0, const float* __restrict__ c1,
    const float* __restrict__ c2, const float* __restrict__ c3,
    float* __restrict__ w0, float* __restrict__ w1,
    float* __restrict__ w2, float* __restrict__ w3)
{
    int g = blockIdx.x * 256 + threadIdx.x;
    const float* src; float* dst; int CI9, CO, loc;
    if (g < 1152)       { src = c0; dst = w0; CI9 = 72;  CO = 16; loc = g; }
    else if (g < 5760)  { src = c1; dst = w1; CI9 = 144; CO = 32; loc = g - 1152; }
    else if (g < 10368) { src = c2; dst = w2; CI9 = 288; CO = 16; loc = g - 5760; }
    else if (g < 14976) { src = c3; dst = w3; CI9 = 144; CO = 32; loc = g - 10368; }
    else return;
    int r = loc / CO, co = loc - r * CO;
    dst[loc] = src[co * CI9 + r];
}

// ---------------------------------------------------------------------------
// Generic row-conv pass.
// item = cog + NCOG*(chunk + NCHUNK*(y + HO*(img + 2*half)))
// Per (ci,ky): NREAD4 ds_read_b128 cover the row window, reused across kx.
// Row offset = y*RS + (y>>1)*SKEW  (monotone skew; same fn on read & write).
// NSPLIT==2: half0 -> sOut0 (bias-init), half1 -> sOutP (zero-init), no relu.
// ---------------------------------------------------------------------------
template<int CI_SUB, int CO, int HO, int WO, int SLOTS, int X0STEP, int NCHUNK,
         int NSPLIT, int IN_RS, int IN_SKEW, int IN_PLANE, int IN_IMG,
         int OUT_RS, int OUT_SKEW, int OUT_PLANE, int OUT_IMG, int NREAD4>
__device__ __forceinline__ void conv_row(
    const float* __restrict__ sIn, float* __restrict__ sOut0,
    float* __restrict__ sOutP, const float* __restrict__ wt,
    const float* __restrict__ bias, int tid)
{
    constexpr int NCOG = CO / 4;
    constexpr int NITEMS = NCOG * NCHUNK * HO * 2 * NSPLIT;
    static_assert(NITEMS <= 256, "single pass");
    if (tid >= NITEMS) return;

    int item = tid;
    const int cog  = item % NCOG;    item /= NCOG;
    const int chunk = item % NCHUNK; item /= NCHUNK;
    const int y    = item % HO;      item /= HO;
    const int img  = item % 2;       item /= 2;
    const int half = item;
    const int x0  = chunk * X0STEP;
    const int ci0 = half * CI_SUB;

    float* __restrict__ sOut = (half == 0) ? sOut0 : sOutP;

    // cc-major accumulators for vectorized writes
    float acc[4][SLOTS];
    if (half == 0) {
        const float4 bv = *(const float4*)(bias + cog * 4);
#pragma unroll
        for (int q = 0; q < SLOTS; q++) {
            acc[0][q] = bv.x; acc[1][q] = bv.y; acc[2][q] = bv.z; acc[3][q] = bv.w;
        }
    } else {
#pragma unroll
        for (int cc = 0; cc < 4; cc++)
#pragma unroll
            for (int q = 0; q < SLOTS; q++) acc[cc][q] = 0.0f;
    }

    int roff[3];
#pragma unroll
    for (int ky = 0; ky < 3; ky++) {
        int yy = y + ky;
        roff[ky] = yy * IN_RS + (yy >> 1) * IN_SKEW;
    }

    const float* __restrict__ inB   = sIn + img * IN_IMG + x0;
    const float* __restrict__ wBase = wt + cog * 4;

#pragma unroll 2
    for (int ci = 0; ci < CI_SUB; ci++) {
        const float* __restrict__ ip = inB + (ci0 + ci) * IN_PLANE;
        const float* __restrict__ wp = wBase + (ci0 + ci) * 9 * CO;
#pragma unroll
        for (int ky = 0; ky < 3; ky++) {
            union { float4 v4[NREAD4]; float xs[NREAD4 * 4]; } xv;
            const float* __restrict__ rp = ip + roff[ky];
#pragma unroll
            for (int j = 0; j < NREAD4; j++)
                xv.v4[j] = *(const float4*)(rp + j * 4);
            float4 w[3];
#pragma unroll
            for (int kx = 0; kx < 3; kx++)
                w[kx] = *(const float4*)(wp + (ky * 3 + kx) * CO);
#pragma unroll
            for (int kx = 0; kx < 3; kx++) {
#pragma unroll
                for (int q = 0; q < SLOTS; q++) {
                    const float iv = xv.xs[q + kx];
                    acc[0][q] += iv * w[kx].x; acc[1][q] += iv * w[kx].y;
                    acc[2][q] += iv * w[kx].z; acc[3][q] += iv * w[kx].w;
                }
            }
        }
    }

    const int nv = (x0 + SLOTS <= WO) ? SLOTS : (WO - x0);
    float* __restrict__ op = sOut + img * OUT_IMG
                           + y * OUT_RS + (y >> 1) * OUT_SKEW + x0;
#pragma unroll
    for (int cc = 0; cc < 4; cc++) {
        float* __restrict__ oc = op + (cog * 4 + cc) * OUT_PLANE;
#pragma unroll
        for (int j = 0; j < SLOTS; j += 4) {
            const int rem = nv - j;
            float v0 = acc[cc][j];
            float v1 = (j + 1 < SLOTS) ? acc[cc][j + 1] : 0.0f;
            float v2 = (j + 2 < SLOTS) ? acc[cc][j + 2] : 0.0f;
            float v3 = (j + 3 < SLOTS) ? acc[cc][j + 3] : 0.0f;
            if (NSPLIT == 1) {
                v0 = fmaxf(v0, 0.0f); v1 = fmaxf(v1, 0.0f);
                v2 = fmaxf(v2, 0.0f); v3 = fmaxf(v3, 0.0f);
            }
            if (rem >= 4) {
                *(float4*)(oc + j) = make_float4(v0, v1, v2, v3);
            } else if (rem == 3) {
                *(float2*)(oc + j) = make_float2(v0, v1);
                oc[j + 2] = v2;
            } else if (rem == 2) {
                *(float2*)(oc + j) = make_float2(v0, v1);
            } else if (rem == 1) {
                oc[j] = v0;
            }
        }
    }
}

__global__ __launch_bounds__(256, 2) void conv_stack5(
    const float* __restrict__ states,
    const float* __restrict__ wt0, const float* __restrict__ cb0,
    const float* __restrict__ wt1, const float* __restrict__ cb1,
    const float* __restrict__ wt2, const float* __restrict__ cb2,
    const float* __restrict__ wt3, const float* __restrict__ cb3,
    float* __restrict__ x0out)
{
    __shared__ float A[ARENA_F];
    const int tid = threadIdx.x;

    // ---- stage input with row re-pad 15 -> stride 20 ----
    const float* gin = states + (size_t)blockIdx.x * 3600;
    for (int e = tid; e < 3600; e += 256) {
        int img = e / 1800, r = e - img * 1800;
        int ci = r / 225;  r -= ci * 225;
        int y = r / 15, x = r - y * 15;
        A[OFF_IN + img * 2400 + ci * 300 + y * 20 + x] = gin[e];
    }
    __syncthreads();

    // L0: 8->16, 15->13. 2 chunks (x0=0,8), SLOTS=8.
    // in rs20/pl300/img2400; out skewed rs16+(y>>1)*4, pl232, img3712
    conv_row<8, 16, 13, 13, 8, 8, 2, 1,
             20, 0, 300, 2400, 16, 4, 232, 3712, 3>(
        A + OFF_IN, A + OFF_L0, A + OFF_L0, wt0, cb0, tid);
    __syncthreads();

    // L1: 16->32, 13->11. SLOTS=11. in skewed rs16+4/pl232/img3712, out rs12/pl132
    conv_row<16, 32, 11, 11, 11, 0, 1, 1,
             16, 4, 232, 3712, 12, 0, 132, 4224, 4>(
        A + OFF_L0, A + OFF_L1, A + OFF_L1, wt1, cb1, tid);
    __syncthreads();

    // L2: 32->16, 11->9.  ci-split x2, SLOTS=9. in rs12/pl132, out rs12/pl108
    conv_row<16, 16, 9, 9, 9, 0, 1, 2,
             12, 0, 132, 4224, 12, 0, 108, 1728, 3>(
        A + OFF_L1, A + OFF_L2, A + OFF_L2P, wt2, cb2, tid);
    __syncthreads();
    // combine halves + relu (in place), float4
    for (int i = tid; i < 864; i += 256) {
        float4 a = *(float4*)(A + OFF_L2 + i * 4);
        float4 b = *(float4*)(A + OFF_L2P + i * 4);
        a.x = fmaxf(a.x + b.x, 0.0f); a.y = fmaxf(a.y + b.y, 0.0f);
        a.z = fmaxf(a.z + b.z, 0.0f); a.w = fmaxf(a.w + b.w, 0.0f);
        *(float4*)(A + OFF_L2 + i * 4) = a;
    }
    __syncthreads();

    // L3: 16->32, 9->7.  ci-split x2, SLOTS=7. in rs12/pl108, out rs8/pl56
    conv_row<8, 32, 7, 7, 7, 0, 1, 2,
             12, 0, 108, 1728, 8, 0, 56, 1792, 3>(
        A + OFF_L2, A + OFF_L3, A + OFF_L3P, wt3, cb3, tid);
    __syncthreads();

    // combine + relu + coalesced global store (flat [img][32*7*7])
    float* gout = x0out + (size_t)blockIdx.x * 3136;
    for (int i = tid; i < 3136; i += 256) {
        int img = i / 1568, r = i - img * 1568;
        int ch = r / 49, p = r - ch * 49;
        int yy = p / 7, xx = p - yy * 7;
        int idx = img * 1792 + ch * 56 + yy * 8 + xx;
        float v = A[OFF_L3 + idx] + A[OFF_L3P + idx];
        gout[i] = fmaxf(v, 0.0f);
    }
}

// ---------------------------------------------------------------------------
// GEMM: C[M x 128] = A[M x K] @ W[K x 128] (+bias)(+relu); M-tile 64
// ---------------------------------------------------------------------------
template<int K, bool RELU>
__global__ __launch_bounds__(256) void gemm128(
    const float* __restrict__ Am, const float* __restrict__ Wm,
    const float* __restrict__ bias, float* __restrict__ Cm)
{
    __shared__ float As[64 * 36];
    __shared__ float Ws[32 * 128];

    const int tid = threadIdx.x;
    const int m0  = blockIdx.x * 64;
    const int rg  = tid >> 4;
    const int cg  = tid & 15;

    float acc[4][8];
#pragma unroll
    for (int r = 0; r < 4; r++)
#pragma unroll
        for (int c = 0; c < 8; c++) acc[r][c] = 0.0f;

    for (int k0 = 0; k0 < K; k0 += 32) {
        __syncthreads();
#pragma unroll
        for (int it = 0; it < 2; it++) {
            int idx = tid + it * 256;
            int row = idx >> 3;
            int c4  = idx & 7;
            float4 v = *(const float4*)(Am + (size_t)(m0 + row) * K + k0 + c4 * 4);
            *(float4*)(As + row * 36 + c4 * 4) = v;
        }
#pragma unroll
        for (int it = 0; it < 4; it++) {
            int idx = tid + it * 256;
            int kr  = idx >> 5;
            int c4  = idx & 31;
            float4 v = *(const float4*)(Wm + (size_t)(k0 + kr) * 128 + c4 * 4);
            *(float4*)(Ws + kr * 128 + c4 * 4) = v;
        }
        __syncthreads();

#pragma unroll
        for (int kk = 0; kk < 32; kk++) {
            float a0 = As[(rg * 4 + 0) * 36 + kk];
            float a1 = As[(rg * 4 + 1) * 36 + kk];
            float a2 = As[(rg * 4 + 2) * 36 + kk];
            float a3 = As[(rg * 4 + 3) * 36 + kk];
            float4 w0 = *(const float4*)(Ws + kk * 128 + cg * 8);
            float4 w1 = *(const float4*)(Ws + kk * 128 + cg * 8 + 4);
            acc[0][0] += a0 * w0.x; acc[0][1] += a0 * w0.y; acc[0][2] += a0 * w0.z; acc[0][3] += a0 * w0.w;
            acc[0][4] += a0 * w1.x; acc[0][5] += a0 * w1.y; acc[0][6] += a0 * w1.z; acc[0][7] += a0 * w1.w;
            acc[1][0] += a1 * w0.x; acc[1][1] += a1 * w0.y; acc[1][2] += a1 * w0.z; acc[1][3] += a1 * w0.w;
            acc[1][4] += a1 * w1.x; acc[1][5] += a1 * w1.y; acc[1][6] += a1 * w1.z; acc[1][7] += a1 * w1.w;
            acc[2][0] += a2 * w0.x; acc[2][1] += a2 * w0.y; acc[2][2] += a2 * w0.z; acc[2][3] += a2 * w0.w;
            acc[2][4] += a2 * w1.x; acc[2][5] += a2 * w1.y; acc[2][6] += a2 * w1.z; acc[2][7] += a2 * w1.w;
            acc[3][0] += a3 * w0.x; acc[3][1] += a3 * w0.y; acc[3][2] += a3 * w0.z; acc[3][3] += a3 * w0.w;
            acc[3][4] += a3 * w1.x; acc[3][5] += a3 * w1.y; acc[3][6] += a3 * w1.z; acc[3][7] += a3 * w1.w;
        }
    }

#pragma unroll
    for (int r = 0; r < 4; r++) {
        int row = m0 + rg * 4 + r;
        float v[8];
#pragma unroll
        for (int c = 0; c < 8; c++) {
            float x = acc[r][c];
            if (bias) x += bias[cg * 8 + c];
            if (RELU) x = fmaxf(x, 0.0f);
            v[c] = x;
        }
        float* gp = Cm + (size_t)row * 128 + cg * 8;
        *(float4*)(gp)     = make_float4(v[0], v[1], v[2], v[3]);
        *(float4*)(gp + 4) = make_float4(v[4], v[5], v[6], v[7]);
    }
}

// ---------------------------------------------------------------------------
// GCN aggregation: out[b,j] = dinv_j * sum_i (adj[b,i,j]*dinv_i*xw[b,i]) + gb
// ---------------------------------------------------------------------------
__global__ __launch_bounds__(256) void gcn_agg(
    const float* __restrict__ adj, const float* __restrict__ xw,
    const float* __restrict__ gb, float* __restrict__ outp)
{
    __shared__ float sAdj[64 * 64];
    __shared__ float sXW[64 * 128];
    __shared__ float sDinv[64];

    const int b = blockIdx.x;
    const int tid = threadIdx.x;

    const float* ga = adj + (size_t)b * 4096;
#pragma unroll
    for (int it = 0; it < 4; it++) {
        int idx = tid + it * 256;
        *(float4*)(sAdj + idx * 4) = *(const float4*)(ga + idx * 4);
    }
    const float* gx = xw + (size_t)b * 8192;
#pragma unroll
    for (int it = 0; it < 8; it++) {
        int idx = tid + it * 256;
        *(float4*)(sXW + idx * 4) = *(const float4*)(gx + idx * 4);
    }
    __syncthreads();

    if (tid < 64) {
        float d = 0.0f;
        for (int i = 0; i < 64; i++) d += sAdj[i * 64 + tid];
        sDinv[tid] = (d > 0.0f) ? rsqrtf(d) : 0.0f;
    }
    __syncthreads();

#pragma unroll
    for (int it = 0; it < 8; it++) {
        int idx = tid + it * 256;
        int i = idx >> 5;
        float s = sDinv[i];
        float4 v = *(float4*)(sXW + idx * 4);
        v.x *= s; v.y *= s; v.z *= s; v.w *= s;
        *(float4*)(sXW + idx * 4) = v;
    }
    __syncthreads();

    const int j  = tid >> 2;
    const int eb = (tid & 3) * 32;
    float acc[32];
#pragma unroll
    for (int e = 0; e < 32; e++) acc[e] = 0.0f;

    for (int i = 0; i < 64; i++) {
        float wgt = sAdj[i * 64 + j];
        const float* xp = sXW + i * 128 + eb;
#pragma unroll
        for (int e4 = 0; e4 < 8; e4++) {
            float4 v = *(const float4*)(xp + e4 * 4);
            acc[e4 * 4 + 0] += wgt * v.x;
            acc[e4 * 4 + 1] += wgt * v.y;
            acc[e4 * 4 + 2] += wgt * v.z;
            acc[e4 * 4 + 3] += wgt * v.w;
        }
    }

    const float dj = sDinv[j];
    float* go = outp + ((size_t)b * 64 + j) * 128 + eb;
#pragma unroll
    for (int e4 = 0; e4 < 8; e4++) {
        float4 v;
        v.x = acc[e4 * 4 + 0] * dj + gb[eb + e4 * 4 + 0];
        v.y = acc[e4 * 4 + 1] * dj + gb[eb + e4 * 4 + 1];
        v.z = acc[e4 * 4 + 2] * dj + gb[eb + e4 * 4 + 2];
        v.w = acc[e4 * 4 + 3] * dj + gb[eb + e4 * 4 + 3];
        *(float4*)(go + e4 * 4) = v;
    }
}

// ---------------------------------------------------------------------------
extern "C" void kernel_launch(void* const* d_in, const int* in_sizes, int n_in,
                              void* d_out, int out_size, void* d_ws, size_t ws_size,
                              hipStream_t stream)
{
    const float* states = (const float*)d_in[0];
    const float* adj    = (const float*)d_in[1];
    const float* cw0 = (const float*)d_in[2];  const float* cb0 = (const float*)d_in[3];
    const float* cw1 = (const float*)d_in[4];  const float* cb1 = (const float*)d_in[5];
    const float* cw2 = (const float*)d_in[6];  const float* cb2 = (const float*)d_in[7];
    const float* cw3 = (const float*)d_in[8];  const float* cb3 = (const float*)d_in[9];
    const float* mw0 = (const float*)d_in[10]; const float* mb0 = (const float*)d_in[11];
    const float* mw1 = (const float*)d_in[12]; const float* mb1 = (const float*)d_in[13];
    const float* mw2 = (const float*)d_in[14]; const float* mb2 = (const float*)d_in[15];
    const float* gw  = (const float*)d_in[16]; const float* gb  = (const float*)d_in[17];

    float* ws = (float*)d_ws;
    float* X0 = ws;                                   // 16384*1568 floats
    float* Bu = ws + (size_t)25690112;                // 16384*128
    float* Cu = Bu + (size_t)2097152;                 // 16384*128
    float* WT0 = Cu + (size_t)2097152;                // 1152
    float* WT1 = WT0 + 1152;                          // 4608
    float* WT2 = WT1 + 4608;                          // 4608
    float* WT3 = WT2 + 4608;                          // 4608

    float* out = (float*)d_out;

    transpose_w<<<59, 256, 0, stream>>>(cw0, cw1, cw2, cw3, WT0, WT1, WT2, WT3);
    conv_stack5<<<NIMG / 2, 256, 0, stream>>>(states, WT0, cb0, WT1, cb1,
                                              WT2, cb2, WT3, cb3, X0);
    gemm128<1568, true ><<<256, 256, 0, stream>>>(X0, mw0, mb0, Bu);   // H1
    gemm128<128,  true ><<<256, 256, 0, stream>>>(Bu, mw1, mb1, Cu);   // H2
    gemm128<128,  false><<<256, 256, 0, stream>>>(Cu, mw2, mb2, Bu);   // feats
    gemm128<128,  false><<<256, 256, 0, stream>>>(Bu, gw, nullptr, Cu);// xw
    gcn_agg<<<256, 256, 0, stream>>>(adj, Cu, gb, out);
}